// Round 8
// baseline (201.314 us; speedup 1.0000x reference)
//
#include <hip/hip_runtime.h>

// ITA integer softmax — register-resident, nt loads+stores, 2 rows per wave
// software-pipelined: 16 loads issued up front; row1 compute overlaps row0
// store drain (removes the per-wave dead store-drain tail before s_endpgm).
//
// x: (2,16,2048,2048) int32 -> out uint8 values stored as int32.
// EPS_MAX = 1.0 exactly, so every float-round shift == integer difference.
// Exact per-row reformulation (K=2048, 128 groups of 16):
//   P_g = prefix-max of group maxima (init -128), d_g = P_g - P_{g-1}
//   s_g = sum_k 256 >> min(P_g - x_k, 31)
//   eps = fold_g: eps = (eps >> min(d_g,31)) + s_g     (exact; eps < 2^20)
//   inv = 65280 / eps ; out_k = inv >> min(M - x_k, 31)
// Lanes 4a..4a+3 jointly hold group g = 16j+a per load j.

typedef int iv4 __attribute__((ext_vector_type(4)));  // ok for nt builtins

constexpr int K = 2048;
constexpr int WAVES_PER_BLOCK = 4;
constexpr int ROWS_PER_WAVE = 2;

__device__ __forceinline__ int2 row_stats(const iv4 (&xv)[8], int lane) {
  int pk[8];
  int A = -128;  // running max (wave-uniform)
#pragma unroll
  for (int j = 0; j < 8; ++j) {
    const iv4 v = xv[j];
    int gm = max(max(v.x, v.y), max(v.z, v.w));
    gm = max(gm, __shfl_xor(gm, 1));
    gm = max(gm, __shfl_xor(gm, 2));
    int cp = gm;  // cluster-inclusive prefix max (values replicated x4)
#pragma unroll
    for (int d = 4; d < 64; d <<= 1) {
      int t = __shfl_up(cp, d);
      if (lane >= d) cp = max(cp, t);
    }
    int ecp = __shfl_up(cp, 4);
    if (lane < 4) ecp = (int)0x80000000;
    const int P = max(A, cp);
    const int Pp = max(A, ecp);
    const int dd = min(P - Pp, 31);
    int sp = (256 >> min(P - v.x, 31)) + (256 >> min(P - v.y, 31)) +
             (256 >> min(P - v.z, 31)) + (256 >> min(P - v.w, 31));
    sp += __shfl_xor(sp, 1);
    sp += __shfl_xor(sp, 2);
    pk[j] = (dd << 16) | sp;
    A = max(A, __shfl(cp, 63));
  }
  int eps = 0;  // exact serial fold over 128 groups (SALU chain via readlane)
#pragma unroll
  for (int j = 0; j < 8; ++j) {
#pragma unroll
    for (int a = 0; a < 16; ++a) {
      const unsigned u = (unsigned)__builtin_amdgcn_readlane(pk[j], 4 * a);
      eps = (eps >> (u >> 16)) + (int)(u & 0xffffu);
    }
  }
  return make_int2(65280 / eps, A);  // {inv, rowmax}; eps >= 256 always
}

__device__ __forceinline__ void row_store(int* orow, const iv4 (&xv)[8],
                                          int inv, int M, int lane) {
#pragma unroll
  for (int j = 0; j < 8; ++j) {
    const iv4 v = xv[j];
    iv4 o;
    o.x = inv >> min(M - v.x, 31);  // inv <= 255: shift>=9 -> 0 == hw >=32 -> 0
    o.y = inv >> min(M - v.y, 31);
    o.z = inv >> min(M - v.z, 31);
    o.w = inv >> min(M - v.w, 31);
    __builtin_nontemporal_store(o, reinterpret_cast<iv4*>(orow + 256 * j + 4 * lane));
  }
}

__global__ __launch_bounds__(256) void ita_softmax_kernel(
    const int* __restrict__ x, int* __restrict__ out, int nrows) {
  const int lane = threadIdx.x & 63;
  const int wave = threadIdx.x >> 6;
  const int row0 = (blockIdx.x * WAVES_PER_BLOCK + wave) * ROWS_PER_WAVE;
  if (row0 >= nrows) return;  // wave-uniform
  const bool has1 = (row0 + 1) < nrows;

  const int* xr0 = x + (size_t)row0 * K;
  iv4 a[8], b[8];
  // ---- issue all 16 nt loads up front (max MLP) ----
#pragma unroll
  for (int j = 0; j < 8; ++j)
    a[j] = __builtin_nontemporal_load(
        reinterpret_cast<const iv4*>(xr0 + 256 * j + 4 * lane));
  if (has1) {
#pragma unroll
    for (int j = 0; j < 8; ++j)
      b[j] = __builtin_nontemporal_load(
          reinterpret_cast<const iv4*>(xr0 + K + 256 * j + 4 * lane));
  }

  // ---- row0: stats+fold, then store burst ----
  const int2 r0 = row_stats(a, lane);
  row_store(out + (size_t)row0 * K, a, r0.x, r0.y, lane);

  // ---- row1 compute overlaps row0 store drain ----
  if (has1) {
    const int2 r1 = row_stats(b, lane);
    row_store(out + (size_t)(row0 + 1) * K, b, r1.x, r1.y, lane);
  }
}

extern "C" void kernel_launch(void* const* d_in, const int* in_sizes, int n_in,
                              void* d_out, int out_size, void* d_ws, size_t ws_size,
                              hipStream_t stream) {
  const int* x = (const int*)d_in[0];
  int* out = (int*)d_out;
  const int nrows = in_sizes[0] / K;
  const int rows_per_block = WAVES_PER_BLOCK * ROWS_PER_WAVE;
  const int blocks = (nrows + rows_per_block - 1) / rows_per_block;
  ita_softmax_kernel<<<blocks, 256, 0, stream>>>(x, out, nrows);
}